// Round 4
// baseline (671.768 us; speedup 1.0000x reference)
//
#include <hip/hip_runtime.h>
#include <hip/hip_bf16.h>

typedef __bf16 bf16_t;
typedef __bf16 bf16x4 __attribute__((ext_vector_type(4)));
typedef __bf16 bf16x8 __attribute__((ext_vector_type(8)));
typedef float f32x4 __attribute__((ext_vector_type(4)));

static constexpr int BB    = 2;
static constexpr int SEQ   = 2048;
static constexpr int DM    = 1024;   // D == INNER
static constexpr int NHEAD = 16;
static constexpr int HD    = 64;
static constexpr float L2E = 1.4426950408889634f;

__device__ __forceinline__ bf16x8 ld8(const bf16_t* p) {
  return *reinterpret_cast<const bf16x8*>(p);
}

// async global->LDS, 16B per lane. LDS dest is wave-uniform base + lane*16.
__device__ __forceinline__ void gl_lds16(const bf16_t* g, bf16_t* l) {
  __builtin_amdgcn_global_load_lds(
      (const __attribute__((address_space(1))) void*)g,
      (__attribute__((address_space(3))) void*)l, 16, 0, 0);
}

template <typename T> __device__ __forceinline__ T cvt_out(float v);
template <> __device__ __forceinline__ float  cvt_out<float >(float v) { return v; }
template <> __device__ __forceinline__ bf16_t cvt_out<bf16_t>(float v) { return (bf16_t)v; }

// ---------------- transpose + cast: in (R,C) fp32 -> out (C,R) bf16 ----------------
__global__ __launch_bounds__(256) void transpose_cast(const float* __restrict__ in,
                                                      bf16_t* __restrict__ out,
                                                      int R, int C) {
  __shared__ float tile[32][33];
  const int c0 = blockIdx.x * 32, r0 = blockIdx.y * 32;
  const int tx = threadIdx.x & 31, ty = threadIdx.x >> 5;
#pragma unroll
  for (int y = ty; y < 32; y += 8)
    tile[y][tx] = in[(size_t)(r0 + y) * C + (c0 + tx)];
  __syncthreads();
#pragma unroll
  for (int y = ty; y < 32; y += 8)
    out[(size_t)(c0 + y) * R + (r0 + tx)] = (bf16_t)tile[tx][y];
}

// -------- LayerNorm row kernel: emits x(bf16), xn(bf16), maskA(float addend) --------
__global__ __launch_bounds__(256) void row_prep(const float* __restrict__ x,
    const float* __restrict__ ln_w, const float* __restrict__ ln_b,
    const int* __restrict__ mask,
    bf16_t* __restrict__ xbf, bf16_t* __restrict__ xn, float* __restrict__ maskA) {
  const int row = blockIdx.x, t = threadIdx.x;
  __shared__ float red[8];
  const float4 xv = *reinterpret_cast<const float4*>(&x[(size_t)row * DM + t * 4]);
  float s  = xv.x + xv.y + xv.z + xv.w;
  float s2 = xv.x * xv.x + xv.y * xv.y + xv.z * xv.z + xv.w * xv.w;
#pragma unroll
  for (int off = 32; off >= 1; off >>= 1) {
    s  += __shfl_xor(s,  off, 64);
    s2 += __shfl_xor(s2, off, 64);
  }
  if ((t & 63) == 0) { red[t >> 6] = s; red[4 + (t >> 6)] = s2; }
  __syncthreads();
  s  = red[0] + red[1] + red[2] + red[3];
  s2 = red[4] + red[5] + red[6] + red[7];
  const float mu   = s * (1.0f / DM);
  const float var  = s2 * (1.0f / DM) - mu * mu;
  const float rstd = rsqrtf(var + 1e-5f);
  const float4 wv = *reinterpret_cast<const float4*>(&ln_w[t * 4]);
  const float4 bv = *reinterpret_cast<const float4*>(&ln_b[t * 4]);
  union { bf16_t h[4]; uint2 u; } p0, p1;
  p0.h[0] = (bf16_t)xv.x; p0.h[1] = (bf16_t)xv.y;
  p0.h[2] = (bf16_t)xv.z; p0.h[3] = (bf16_t)xv.w;
  p1.h[0] = (bf16_t)((xv.x - mu) * rstd * wv.x + bv.x);
  p1.h[1] = (bf16_t)((xv.y - mu) * rstd * wv.y + bv.y);
  p1.h[2] = (bf16_t)((xv.z - mu) * rstd * wv.z + bv.z);
  p1.h[3] = (bf16_t)((xv.w - mu) * rstd * wv.w + bv.w);
  *reinterpret_cast<uint2*>(&xbf[(size_t)row * DM + t * 4]) = p0.u;
  *reinterpret_cast<uint2*>(&xn [(size_t)row * DM + t * 4]) = p1.u;
  if (t == 0) maskA[row] = mask[row] ? 0.0f : -1e30f;
}

// ---- m97-style 128x128 bf16 MFMA GEMM: C(M,Nn) = A(M,K)*Bt(Nn,K)^T, BK=32 ----
template <typename OutT>
__global__ __launch_bounds__(256) void gemm128(const bf16_t* __restrict__ A,
    const bf16_t* __restrict__ Bt, OutT* __restrict__ C,
    int M, int Nn, int K, float scale) {
  __shared__ alignas(16) bf16_t As[128 * 32];
  __shared__ alignas(16) bf16_t Bs[128 * 32];
  const int m0 = blockIdx.x * 128, n0 = blockIdx.y * 128;
  const int t = threadIdx.x, lane = t & 63, w = t >> 6;
  const int wm = (w & 1) * 64, wn = (w >> 1) * 64;
  const int l15 = lane & 15, q4 = lane >> 4;
  f32x4 acc[4][4] = {};
  const int sr = lane >> 2, sc = (lane & 3) * 8;   // 16 rows x 32 cols per issue
  const bf16_t* Ap0 = A  + (size_t)(m0 + w * 32 + sr) * K + sc;
  const bf16_t* Ap1 = Ap0 + (size_t)16 * K;
  const bf16_t* Bp0 = Bt + (size_t)(n0 + w * 32 + sr) * K + sc;
  const bf16_t* Bp1 = Bp0 + (size_t)16 * K;
  bf16_t* AsL0 = &As[(w * 32) * 32];
  bf16_t* AsL1 = &As[(w * 32 + 16) * 32];
  bf16_t* BsL0 = &Bs[(w * 32) * 32];
  bf16_t* BsL1 = &Bs[(w * 32 + 16) * 32];
  for (int k0 = 0; k0 < K; k0 += 32) {
    gl_lds16(Ap0 + k0, AsL0);
    gl_lds16(Ap1 + k0, AsL1);
    gl_lds16(Bp0 + k0, BsL0);
    gl_lds16(Bp1 + k0, BsL1);
    __syncthreads();
    bf16x8 af[4], bfr[4];
#pragma unroll
    for (int mt = 0; mt < 4; ++mt) af[mt]  = ld8(&As[(wm + mt * 16 + l15) * 32 + q4 * 8]);
#pragma unroll
    for (int nt = 0; nt < 4; ++nt) bfr[nt] = ld8(&Bs[(wn + nt * 16 + l15) * 32 + q4 * 8]);
#pragma unroll
    for (int mt = 0; mt < 4; ++mt)
#pragma unroll
      for (int nt = 0; nt < 4; ++nt)
        acc[mt][nt] = __builtin_amdgcn_mfma_f32_16x16x32_bf16(af[mt], bfr[nt], acc[mt][nt], 0, 0, 0);
    __syncthreads();
  }
#pragma unroll
  for (int mt = 0; mt < 4; ++mt)
#pragma unroll
    for (int nt = 0; nt < 4; ++nt)
#pragma unroll
      for (int r = 0; r < 4; ++r) {
        const int gm = m0 + wm + mt * 16 + q4 * 4 + r;
        const int gn = n0 + wn + nt * 16 + l15;
        C[(size_t)gm * Nn + gn] = cvt_out<OutT>(acc[mt][nt][r] * scale);
      }
}

// ---- 128x64 GEMM with kv-split epilogue: C=K (B*SEQ,64), C2=V^T (B,64,SEQ) ----
__global__ __launch_bounds__(256) void gemm_kv(const bf16_t* __restrict__ A,
    const bf16_t* __restrict__ Bt, bf16_t* __restrict__ C, bf16_t* __restrict__ C2,
    int M, int Nn, int K) {
  __shared__ alignas(16) bf16_t As[128 * 32];
  __shared__ alignas(16) bf16_t Bs[64 * 32];
  const int m0 = blockIdx.x * 128, n0 = blockIdx.y * 64;
  const int t = threadIdx.x, lane = t & 63, w = t >> 6;
  const int wm = (w & 1) * 64, wn = (w >> 1) * 32;
  const int l15 = lane & 15, q4 = lane >> 4;
  f32x4 acc[4][2] = {};
  const int sr = lane >> 2, sc = (lane & 3) * 8;
  const bf16_t* Ap0 = A  + (size_t)(m0 + w * 32 + sr) * K + sc;
  const bf16_t* Ap1 = Ap0 + (size_t)16 * K;
  const bf16_t* Bp  = Bt + (size_t)(n0 + w * 16 + sr) * K + sc;
  bf16_t* AsL0 = &As[(w * 32) * 32];
  bf16_t* AsL1 = &As[(w * 32 + 16) * 32];
  bf16_t* BsL  = &Bs[(w * 16) * 32];
  for (int k0 = 0; k0 < K; k0 += 32) {
    gl_lds16(Ap0 + k0, AsL0);
    gl_lds16(Ap1 + k0, AsL1);
    gl_lds16(Bp  + k0, BsL);
    __syncthreads();
    bf16x8 af[4], bfr[2];
#pragma unroll
    for (int mt = 0; mt < 4; ++mt) af[mt]  = ld8(&As[(wm + mt * 16 + l15) * 32 + q4 * 8]);
#pragma unroll
    for (int nt = 0; nt < 2; ++nt) bfr[nt] = ld8(&Bs[(wn + nt * 16 + l15) * 32 + q4 * 8]);
#pragma unroll
    for (int mt = 0; mt < 4; ++mt)
#pragma unroll
      for (int nt = 0; nt < 2; ++nt)
        acc[mt][nt] = __builtin_amdgcn_mfma_f32_16x16x32_bf16(af[mt], bfr[nt], acc[mt][nt], 0, 0, 0);
    __syncthreads();
  }
#pragma unroll
  for (int mt = 0; mt < 4; ++mt)
#pragma unroll
    for (int nt = 0; nt < 2; ++nt)
#pragma unroll
      for (int r = 0; r < 4; ++r) {
        const int gm = m0 + wm + mt * 16 + q4 * 4 + r;
        const int gn = n0 + wn + nt * 16 + l15;
        const bf16_t ov = (bf16_t)acc[mt][nt][r];
        if (gn < HD) C[(size_t)gm * HD + gn] = ov;
        else C2[((size_t)(gm >> 11) * HD + (gn - HD)) * SEQ + (gm & 2047)] = ov;
      }
}

// ------- flash attention v4: b-PAIRED blocks (bias loaded once, used for both
//         batches), S^T orientation, 64 q-rows/block, 64-key tiles,
//         single-buffered K/V (2 barriers/iter), reg-prefetch of next K/V -------
__global__ __launch_bounds__(256, 3) void flash_attn(
    const bf16_t* __restrict__ q,     // (B, SEQ, DM), head h at cols h*64..
    const bf16_t* __restrict__ kk,    // (B, SEQ, HD)
    const bf16_t* __restrict__ vT,    // (B, HD, SEQ)
    const float*  __restrict__ bias,  // (NHEAD, SEQ, SEQ)
    const float*  __restrict__ maskA, // (B, SEQ): 0 or -1e30
    bf16_t* __restrict__ aout)        // (B, SEQ, DM)
{
  const int h  = blockIdx.y;          // 16 heads
  const int i0 = blockIdx.x * 64;     // 32 query tiles
  const int t = threadIdx.x, lane = t & 63, w = t >> 6;
  const int l15 = lane & 15, q4 = lane >> 4;

  __shared__ alignas(16) bf16_t Ks[2][64][72];   // [b][key][dh]
  __shared__ alignas(16) bf16_t Vs[2][64][72];   // [b][dh][key]
  __shared__ alignas(16) bf16_t Pt[4][16][72];   // per wave: [query][key]

  // Q fragments for both b, direct from global (B-operand: B[k=dh][n=query=l15])
  bf16x8 bq[2][2];
#pragma unroll
  for (int b = 0; b < 2; ++b) {
    const bf16_t* qrow = &q[((size_t)b * SEQ + i0 + w * 16 + l15) * DM + h * HD];
    bq[b][0] = ld8(qrow + q4 * 8);
    bq[b][1] = ld8(qrow + 32 + q4 * 8);
  }

  f32x4 o[2][4] = {};
  float m_run[2] = {-1e30f, -1e30f};
  float l_run[2] = {0.0f, 0.0f};

  const float* bias_p = bias + (size_t)h * SEQ * SEQ
                      + (size_t)(i0 + w * 16 + l15) * SEQ + q4 * 4;

  // staging: each thread covers 16 cols of one row per tile
  const int sr = t >> 2, sc = (t & 3) * 16;
  const bf16_t* kp[2];
  const bf16_t* vp[2];
#pragma unroll
  for (int b = 0; b < 2; ++b) {
    kp[b] = &kk[((size_t)b * SEQ + sr) * HD + sc];
    vp[b] = &vT[((size_t)b * HD + sr) * SEQ + sc];
  }

  uint4 kr[2][2], vr[2][2];
#pragma unroll
  for (int b = 0; b < 2; ++b) {
    kr[b][0] = *reinterpret_cast<const uint4*>(kp[b]);
    kr[b][1] = *reinterpret_cast<const uint4*>(kp[b] + 8);
    vr[b][0] = *reinterpret_cast<const uint4*>(vp[b]);
    vr[b][1] = *reinterpret_cast<const uint4*>(vp[b] + 8);
  }
#pragma unroll
  for (int b = 0; b < 2; ++b) {
    *reinterpret_cast<uint4*>(&Ks[b][sr][sc])     = kr[b][0];
    *reinterpret_cast<uint4*>(&Ks[b][sr][sc + 8]) = kr[b][1];
    *reinterpret_cast<uint4*>(&Vs[b][sr][sc])     = vr[b][0];
    *reinterpret_cast<uint4*>(&Vs[b][sr][sc + 8]) = vr[b][1];
  }
  __syncthreads();

  for (int it = 0; it < SEQ / 64; ++it) {
    const int j0 = it * 64;
    const int j1 = j0 + 64;
    const bool more = (j1 < SEQ);
    if (more) {   // prefetch next K/V tiles into regs (latency hidden by body)
#pragma unroll
      for (int b = 0; b < 2; ++b) {
        kr[b][0] = *reinterpret_cast<const uint4*>(kp[b] + (size_t)j1 * HD);
        kr[b][1] = *reinterpret_cast<const uint4*>(kp[b] + (size_t)j1 * HD + 8);
        vr[b][0] = *reinterpret_cast<const uint4*>(vp[b] + j1);
        vr[b][1] = *reinterpret_cast<const uint4*>(vp[b] + j1 + 8);
      }
    }

    // bias for this tile: shared between both batches (the whole point)
    f32x4 bv[4];
#pragma unroll
    for (int mt = 0; mt < 4; ++mt)
      bv[mt] = *reinterpret_cast<const f32x4*>(bias_p + j0 + mt * 16);

    // S^T for both b: D[m=key][n=query] = K·Q^T
    f32x4 s[2][4];
#pragma unroll
    for (int b = 0; b < 2; ++b)
#pragma unroll
      for (int mt = 0; mt < 4; ++mt) {
        const bf16x8 a0 = ld8(&Ks[b][mt * 16 + l15][q4 * 8]);
        const bf16x8 a1 = ld8(&Ks[b][mt * 16 + l15][32 + q4 * 8]);
        f32x4 z = {0.f, 0.f, 0.f, 0.f};
        z = __builtin_amdgcn_mfma_f32_16x16x32_bf16(a0, bq[b][0], z, 0, 0, 0);
        z = __builtin_amdgcn_mfma_f32_16x16x32_bf16(a1, bq[b][1], z, 0, 0, 0);
        s[b][mt] = z;
      }

    // softmax + PV per b (two independent chains; Pt reused wave-locally)
#pragma unroll
    for (int b = 0; b < 2; ++b) {
      f32x4 mv[4];
#pragma unroll
      for (int mt = 0; mt < 4; ++mt)
        mv[mt] = *reinterpret_cast<const f32x4*>(maskA + b * SEQ + j0 + mt * 16 + q4 * 4);

      float mx = -1e30f;
#pragma unroll
      for (int mt = 0; mt < 4; ++mt)
#pragma unroll
        for (int r = 0; r < 4; ++r) {
          s[b][mt][r] = s[b][mt][r] + bv[mt][r] + mv[mt][r];
          mx = fmaxf(mx, s[b][mt][r]);
        }
      mx = fmaxf(mx, __shfl_xor(mx, 16, 64));
      mx = fmaxf(mx, __shfl_xor(mx, 32, 64));
      const float mnew  = fmaxf(m_run[b], mx);
      const float alpha = __builtin_amdgcn_exp2f((m_run[b] - mnew) * L2E);
      const float cc    = -mnew * L2E;
      m_run[b] = mnew;

      float su = 0.0f;
#pragma unroll
      for (int mt = 0; mt < 4; ++mt)
#pragma unroll
        for (int r = 0; r < 4; ++r) {
          s[b][mt][r] = __builtin_amdgcn_exp2f(__builtin_fmaf(s[b][mt][r], L2E, cc));
          su += s[b][mt][r];
        }
      su += __shfl_xor(su, 16, 64);
      su += __shfl_xor(su, 32, 64);
      l_run[b] = l_run[b] * alpha + su;

      // P^T -> Pt[query][key] (4 adjacent keys per b64 write), wave-local
#pragma unroll
      for (int mt = 0; mt < 4; ++mt) {
        union { bf16_t hh[4]; uint2 u; } pu;
        pu.hh[0] = (bf16_t)s[b][mt][0]; pu.hh[1] = (bf16_t)s[b][mt][1];
        pu.hh[2] = (bf16_t)s[b][mt][2]; pu.hh[3] = (bf16_t)s[b][mt][3];
        *reinterpret_cast<uint2*>(&Pt[w][l15][mt * 16 + q4 * 4]) = pu.u;
      }

      // rescale O by alpha of query q4*4+r
#pragma unroll
      for (int r = 0; r < 4; ++r) {
        const float a_r = __shfl(alpha, q4 * 4 + r, 64);
        o[b][0][r] *= a_r; o[b][1][r] *= a_r; o[b][2][r] *= a_r; o[b][3][r] *= a_r;
      }

      // O[m=query][n=dh] += P·V
#pragma unroll
      for (int ks = 0; ks < 2; ++ks) {
        const bf16x8 pf = ld8(&Pt[w][l15][ks * 32 + q4 * 8]);
#pragma unroll
        for (int nt = 0; nt < 4; ++nt) {
          const bf16x8 vv = ld8(&Vs[b][nt * 16 + l15][ks * 32 + q4 * 8]);
          o[b][nt] = __builtin_amdgcn_mfma_f32_16x16x32_bf16(pf, vv, o[b][nt], 0, 0, 0);
        }
      }
    }

    __syncthreads();                 // all waves done reading K/V
    if (more) {
#pragma unroll
      for (int b = 0; b < 2; ++b) {
        *reinterpret_cast<uint4*>(&Ks[b][sr][sc])     = kr[b][0];
        *reinterpret_cast<uint4*>(&Ks[b][sr][sc + 8]) = kr[b][1];
        *reinterpret_cast<uint4*>(&Vs[b][sr][sc])     = vr[b][0];
        *reinterpret_cast<uint4*>(&Vs[b][sr][sc + 8]) = vr[b][1];
      }
    }
    __syncthreads();                 // new tiles visible
  }

#pragma unroll
  for (int b = 0; b < 2; ++b)
#pragma unroll
    for (int r = 0; r < 4; ++r) {
      const float linv = 1.0f / __shfl(l_run[b], q4 * 4 + r, 64);
      const int gi = i0 + w * 16 + q4 * 4 + r;
      bf16_t* dst = &aout[((size_t)b * SEQ + gi) * DM + h * HD];
#pragma unroll
      for (int nt = 0; nt < 4; ++nt)
        dst[nt * 16 + l15] = (bf16_t)(o[b][nt][r] * linv);
    }
}

extern "C" void kernel_launch(void* const* d_in, const int* in_sizes, int n_in,
                              void* d_out, int out_size, void* d_ws, size_t ws_size,
                              hipStream_t stream) {
  const float* x         = (const float*)d_in[0];
  const float* attn_bias = (const float*)d_in[1];
  const float* ln_w      = (const float*)d_in[2];
  const float* ln_b      = (const float*)d_in[3];
  const float* wq        = (const float*)d_in[4];
  const float* wkv       = (const float*)d_in[5];
  const float* wo        = (const float*)d_in[6];
  const int*   mask      = (const int*)d_in[7];
  float* out = (float*)d_out;

  char* ws = (char*)d_ws;
  size_t off = 0;
  auto alloc = [&](size_t bytes) {
    char* p = ws + off;
    off += (bytes + 255) & ~(size_t)255;
    return p;
  };
  bf16_t* xbf   = (bf16_t*)alloc((size_t)BB * SEQ * DM * 2);
  bf16_t* xn    = (bf16_t*)alloc((size_t)BB * SEQ * DM * 2);
  bf16_t* wqT   = (bf16_t*)alloc((size_t)DM * DM * 2);
  bf16_t* wkvT  = (bf16_t*)alloc((size_t)2 * HD * DM * 2);
  bf16_t* woT   = (bf16_t*)alloc((size_t)DM * DM * 2);
  bf16_t* qb    = (bf16_t*)alloc((size_t)BB * SEQ * DM * 2);
  bf16_t* kkb   = (bf16_t*)alloc((size_t)BB * SEQ * HD * 2);
  bf16_t* vTb   = (bf16_t*)alloc((size_t)BB * HD * SEQ * 2);
  bf16_t* aoutb = (bf16_t*)alloc((size_t)BB * SEQ * DM * 2);
  float*  maskA = (float*)alloc((size_t)BB * SEQ * 4);

  transpose_cast<<<dim3(DM / 32, DM / 32), 256, 0, stream>>>(wq, wqT, DM, DM);
  transpose_cast<<<dim3(128 / 32, DM / 32), 256, 0, stream>>>(wkv, wkvT, DM, 128);
  transpose_cast<<<dim3(DM / 32, DM / 32), 256, 0, stream>>>(wo, woT, DM, DM);
  row_prep<<<BB * SEQ, 256, 0, stream>>>(x, ln_w, ln_b, mask, xbf, xn, maskA);
  // q = xn @ wq, scaled by DH^-0.5
  gemm128<bf16_t><<<dim3(32, 8), 256, 0, stream>>>(xn, wqT, qb, BB * SEQ, DM, DM, 0.125f);
  // kv = x @ wkv -> K (B,SEQ,64) and V^T (B,64,SEQ)
  gemm_kv<<<dim3(32, 2), 256, 0, stream>>>(xbf, wkvT, kkb, vTb, BB * SEQ, 128, DM);
  // b-paired flash: grid (query tiles, heads)
  flash_attn<<<dim3(SEQ / 64, NHEAD), 256, 0, stream>>>(qb, kkb, vTb, attn_bias,
                                                        maskA, aoutb);
  // out = aout @ wo (fp32 output)
  gemm128<float><<<dim3(32, 8), 256, 0, stream>>>(aoutb, woT, out, BB * SEQ, DM, DM, 1.0f);
}

// Round 5
// 637.197 us; speedup vs baseline: 1.0543x; 1.0543x over previous
//
#include <hip/hip_runtime.h>
#include <hip/hip_bf16.h>

typedef __bf16 bf16_t;
typedef __bf16 bf16x4 __attribute__((ext_vector_type(4)));
typedef __bf16 bf16x8 __attribute__((ext_vector_type(8)));
typedef float f32x4 __attribute__((ext_vector_type(4)));

static constexpr int BB    = 2;
static constexpr int SEQ   = 2048;
static constexpr int DM    = 1024;   // D == INNER
static constexpr int NHEAD = 16;
static constexpr int HD    = 64;
static constexpr float L2E = 1.4426950408889634f;

__device__ __forceinline__ bf16x8 ld8(const bf16_t* p) {
  return *reinterpret_cast<const bf16x8*>(p);
}

// async global->LDS, 16B per lane. LDS dest is wave-uniform base + lane*16.
__device__ __forceinline__ void gl_lds16(const bf16_t* g, bf16_t* l) {
  __builtin_amdgcn_global_load_lds(
      (const __attribute__((address_space(1))) void*)g,
      (__attribute__((address_space(3))) void*)l, 16, 0, 0);
}

__device__ __forceinline__ uint2 shfl2(uint2 v, int src) {
  uint2 r;
  r.x = (unsigned)__shfl((int)v.x, src, 64);
  r.y = (unsigned)__shfl((int)v.y, src, 64);
  return r;
}

template <typename T> __device__ __forceinline__ T cvt_out(float v);
template <> __device__ __forceinline__ float  cvt_out<float >(float v) { return v; }
template <> __device__ __forceinline__ bf16_t cvt_out<bf16_t>(float v) { return (bf16_t)v; }

// ---------------- transpose + cast: in (R,C) fp32 -> out (C,R) bf16 ----------------
__global__ __launch_bounds__(256) void transpose_cast(const float* __restrict__ in,
                                                      bf16_t* __restrict__ out,
                                                      int R, int C) {
  __shared__ float tile[32][33];
  const int c0 = blockIdx.x * 32, r0 = blockIdx.y * 32;
  const int tx = threadIdx.x & 31, ty = threadIdx.x >> 5;
#pragma unroll
  for (int y = ty; y < 32; y += 8)
    tile[y][tx] = in[(size_t)(r0 + y) * C + (c0 + tx)];
  __syncthreads();
#pragma unroll
  for (int y = ty; y < 32; y += 8)
    out[(size_t)(c0 + y) * R + (r0 + tx)] = (bf16_t)tile[tx][y];
}

// -------- LayerNorm row kernel: emits x(bf16), xn(bf16), maskA(float addend) --------
__global__ __launch_bounds__(256) void row_prep(const float* __restrict__ x,
    const float* __restrict__ ln_w, const float* __restrict__ ln_b,
    const int* __restrict__ mask,
    bf16_t* __restrict__ xbf, bf16_t* __restrict__ xn, float* __restrict__ maskA) {
  const int row = blockIdx.x, t = threadIdx.x;
  __shared__ float red[8];
  const float4 xv = *reinterpret_cast<const float4*>(&x[(size_t)row * DM + t * 4]);
  float s  = xv.x + xv.y + xv.z + xv.w;
  float s2 = xv.x * xv.x + xv.y * xv.y + xv.z * xv.z + xv.w * xv.w;
#pragma unroll
  for (int off = 32; off >= 1; off >>= 1) {
    s  += __shfl_xor(s,  off, 64);
    s2 += __shfl_xor(s2, off, 64);
  }
  if ((t & 63) == 0) { red[t >> 6] = s; red[4 + (t >> 6)] = s2; }
  __syncthreads();
  s  = red[0] + red[1] + red[2] + red[3];
  s2 = red[4] + red[5] + red[6] + red[7];
  const float mu   = s * (1.0f / DM);
  const float var  = s2 * (1.0f / DM) - mu * mu;
  const float rstd = rsqrtf(var + 1e-5f);
  const float4 wv = *reinterpret_cast<const float4*>(&ln_w[t * 4]);
  const float4 bv = *reinterpret_cast<const float4*>(&ln_b[t * 4]);
  union { bf16_t h[4]; uint2 u; } p0, p1;
  p0.h[0] = (bf16_t)xv.x; p0.h[1] = (bf16_t)xv.y;
  p0.h[2] = (bf16_t)xv.z; p0.h[3] = (bf16_t)xv.w;
  p1.h[0] = (bf16_t)((xv.x - mu) * rstd * wv.x + bv.x);
  p1.h[1] = (bf16_t)((xv.y - mu) * rstd * wv.y + bv.y);
  p1.h[2] = (bf16_t)((xv.z - mu) * rstd * wv.z + bv.z);
  p1.h[3] = (bf16_t)((xv.w - mu) * rstd * wv.w + bv.w);
  *reinterpret_cast<uint2*>(&xbf[(size_t)row * DM + t * 4]) = p0.u;
  *reinterpret_cast<uint2*>(&xn [(size_t)row * DM + t * 4]) = p1.u;
  if (t == 0) maskA[row] = mask[row] ? 0.0f : -1e30f;
}

// ---- m97-style 128x128 bf16 MFMA GEMM: C(M,Nn) = A(M,K)*Bt(Nn,K)^T, BK=32 ----
template <typename OutT>
__global__ __launch_bounds__(256) void gemm128(const bf16_t* __restrict__ A,
    const bf16_t* __restrict__ Bt, OutT* __restrict__ C,
    int M, int Nn, int K, float scale) {
  __shared__ alignas(16) bf16_t As[128 * 32];
  __shared__ alignas(16) bf16_t Bs[128 * 32];
  const int m0 = blockIdx.x * 128, n0 = blockIdx.y * 128;
  const int t = threadIdx.x, lane = t & 63, w = t >> 6;
  const int wm = (w & 1) * 64, wn = (w >> 1) * 64;
  const int l15 = lane & 15, q4 = lane >> 4;
  f32x4 acc[4][4] = {};
  const int sr = lane >> 2, sc = (lane & 3) * 8;   // 16 rows x 32 cols per issue
  const bf16_t* Ap0 = A  + (size_t)(m0 + w * 32 + sr) * K + sc;
  const bf16_t* Ap1 = Ap0 + (size_t)16 * K;
  const bf16_t* Bp0 = Bt + (size_t)(n0 + w * 32 + sr) * K + sc;
  const bf16_t* Bp1 = Bp0 + (size_t)16 * K;
  bf16_t* AsL0 = &As[(w * 32) * 32];
  bf16_t* AsL1 = &As[(w * 32 + 16) * 32];
  bf16_t* BsL0 = &Bs[(w * 32) * 32];
  bf16_t* BsL1 = &Bs[(w * 32 + 16) * 32];
  for (int k0 = 0; k0 < K; k0 += 32) {
    gl_lds16(Ap0 + k0, AsL0);
    gl_lds16(Ap1 + k0, AsL1);
    gl_lds16(Bp0 + k0, BsL0);
    gl_lds16(Bp1 + k0, BsL1);
    __syncthreads();
    bf16x8 af[4], bfr[4];
#pragma unroll
    for (int mt = 0; mt < 4; ++mt) af[mt]  = ld8(&As[(wm + mt * 16 + l15) * 32 + q4 * 8]);
#pragma unroll
    for (int nt = 0; nt < 4; ++nt) bfr[nt] = ld8(&Bs[(wn + nt * 16 + l15) * 32 + q4 * 8]);
#pragma unroll
    for (int mt = 0; mt < 4; ++mt)
#pragma unroll
      for (int nt = 0; nt < 4; ++nt)
        acc[mt][nt] = __builtin_amdgcn_mfma_f32_16x16x32_bf16(af[mt], bfr[nt], acc[mt][nt], 0, 0, 0);
    __syncthreads();
  }
#pragma unroll
  for (int mt = 0; mt < 4; ++mt)
#pragma unroll
    for (int nt = 0; nt < 4; ++nt)
#pragma unroll
      for (int r = 0; r < 4; ++r) {
        const int gm = m0 + wm + mt * 16 + q4 * 4 + r;
        const int gn = n0 + wn + nt * 16 + l15;
        C[(size_t)gm * Nn + gn] = cvt_out<OutT>(acc[mt][nt][r] * scale);
      }
}

// ---- 128x64 GEMM with kv-split epilogue: C=K (B*SEQ,64), C2=V^T (B,64,SEQ) ----
__global__ __launch_bounds__(256) void gemm_kv(const bf16_t* __restrict__ A,
    const bf16_t* __restrict__ Bt, bf16_t* __restrict__ C, bf16_t* __restrict__ C2,
    int M, int Nn, int K) {
  __shared__ alignas(16) bf16_t As[128 * 32];
  __shared__ alignas(16) bf16_t Bs[64 * 32];
  const int m0 = blockIdx.x * 128, n0 = blockIdx.y * 64;
  const int t = threadIdx.x, lane = t & 63, w = t >> 6;
  const int wm = (w & 1) * 64, wn = (w >> 1) * 32;
  const int l15 = lane & 15, q4 = lane >> 4;
  f32x4 acc[4][2] = {};
  const int sr = lane >> 2, sc = (lane & 3) * 8;
  const bf16_t* Ap0 = A  + (size_t)(m0 + w * 32 + sr) * K + sc;
  const bf16_t* Ap1 = Ap0 + (size_t)16 * K;
  const bf16_t* Bp  = Bt + (size_t)(n0 + w * 16 + sr) * K + sc;
  bf16_t* AsL0 = &As[(w * 32) * 32];
  bf16_t* AsL1 = &As[(w * 32 + 16) * 32];
  bf16_t* BsL  = &Bs[(w * 16) * 32];
  for (int k0 = 0; k0 < K; k0 += 32) {
    gl_lds16(Ap0 + k0, AsL0);
    gl_lds16(Ap1 + k0, AsL1);
    gl_lds16(Bp  + k0, BsL);
    __syncthreads();
    bf16x8 af[4], bfr[2];
#pragma unroll
    for (int mt = 0; mt < 4; ++mt) af[mt]  = ld8(&As[(wm + mt * 16 + l15) * 32 + q4 * 8]);
#pragma unroll
    for (int nt = 0; nt < 2; ++nt) bfr[nt] = ld8(&Bs[(wn + nt * 16 + l15) * 32 + q4 * 8]);
#pragma unroll
    for (int mt = 0; mt < 4; ++mt)
#pragma unroll
      for (int nt = 0; nt < 2; ++nt)
        acc[mt][nt] = __builtin_amdgcn_mfma_f32_16x16x32_bf16(af[mt], bfr[nt], acc[mt][nt], 0, 0, 0);
    __syncthreads();
  }
#pragma unroll
  for (int mt = 0; mt < 4; ++mt)
#pragma unroll
    for (int nt = 0; nt < 2; ++nt)
#pragma unroll
      for (int r = 0; r < 4; ++r) {
        const int gm = m0 + wm + mt * 16 + q4 * 4 + r;
        const int gn = n0 + wn + nt * 16 + l15;
        const bf16_t ov = (bf16_t)acc[mt][nt][r];
        if (gn < HD) C[(size_t)gm * HD + gn] = ov;
        else C2[((size_t)(gm >> 11) * HD + (gn - HD)) * SEQ + (gm & 2047)] = ov;
      }
}

// ------- flash attention v5: b-paired blocks (bias loaded ONCE per (h,i0,j0),
//         used for both batches), SEQUENTIAL per-b softmax (one s[4] live),
//         S^T orientation, 64 q/block, 64-key tiles, reg-prefetch K/V,
//         shfl-based P transpose, no min-waves bound (VGPRs are free at
//         2 blocks/CU: grid 512 -> 2 blocks x 4 waves = 8 waves/CU). -------
__global__ __launch_bounds__(256) void flash_attn(
    const bf16_t* __restrict__ q,     // (B, SEQ, DM), head h at cols h*64..
    const bf16_t* __restrict__ kk,    // (B, SEQ, HD)
    const bf16_t* __restrict__ vT,    // (B, HD, SEQ)
    const float*  __restrict__ bias,  // (NHEAD, SEQ, SEQ)
    const float*  __restrict__ maskA, // (B, SEQ): 0 or -1e30
    bf16_t* __restrict__ aout)        // (B, SEQ, DM)
{
  const int h  = blockIdx.y;          // 16 heads
  const int i0 = blockIdx.x * 64;     // 32 query tiles
  const int t = threadIdx.x, lane = t & 63, w = t >> 6;
  const int l15 = lane & 15, q4 = lane >> 4;

  __shared__ alignas(16) bf16_t Ks[2][64][72];   // [b][key][dh]
  __shared__ alignas(16) bf16_t Vs[2][64][72];   // [b][dh][key]

  // Q fragments for both b (B-operand: B[k=dh][n=query=l15])
  bf16x8 bq[2][2];
#pragma unroll
  for (int b = 0; b < 2; ++b) {
    const bf16_t* qrow = &q[((size_t)b * SEQ + i0 + w * 16 + l15) * DM + h * HD];
    bq[b][0] = ld8(qrow + q4 * 8);
    bq[b][1] = ld8(qrow + 32 + q4 * 8);
  }

  f32x4 o[2][4] = {};
  float m_run[2] = {-1e30f, -1e30f};
  float l_run[2] = {0.0f, 0.0f};

  const float* bias_p = bias + (size_t)h * SEQ * SEQ
                      + (size_t)(i0 + w * 16 + l15) * SEQ + q4 * 4;

  const int sr = t >> 2, sc = (t & 3) * 16;
  const bf16_t* kp[2];
  const bf16_t* vp[2];
#pragma unroll
  for (int b = 0; b < 2; ++b) {
    kp[b] = &kk[((size_t)b * SEQ + sr) * HD + sc];
    vp[b] = &vT[((size_t)b * HD + sr) * SEQ + sc];
  }

  // prologue: tile 0 for both b
  uint4 kr[2][2], vr[2][2];
#pragma unroll
  for (int b = 0; b < 2; ++b) {
    kr[b][0] = *reinterpret_cast<const uint4*>(kp[b]);
    kr[b][1] = *reinterpret_cast<const uint4*>(kp[b] + 8);
    vr[b][0] = *reinterpret_cast<const uint4*>(vp[b]);
    vr[b][1] = *reinterpret_cast<const uint4*>(vp[b] + 8);
  }
#pragma unroll
  for (int b = 0; b < 2; ++b) {
    *reinterpret_cast<uint4*>(&Ks[b][sr][sc])     = kr[b][0];
    *reinterpret_cast<uint4*>(&Ks[b][sr][sc + 8]) = kr[b][1];
    *reinterpret_cast<uint4*>(&Vs[b][sr][sc])     = vr[b][0];
    *reinterpret_cast<uint4*>(&Vs[b][sr][sc + 8]) = vr[b][1];
  }
  __syncthreads();

  for (int it = 0; it < SEQ / 64; ++it) {
    const int j0 = it * 64;
    const int j1 = j0 + 64;
    const bool more = (j1 < SEQ);
    if (more) {   // reg-prefetch next K/V tiles (latency hidden by the body)
#pragma unroll
      for (int b = 0; b < 2; ++b) {
        kr[b][0] = *reinterpret_cast<const uint4*>(kp[b] + (size_t)j1 * HD);
        kr[b][1] = *reinterpret_cast<const uint4*>(kp[b] + (size_t)j1 * HD + 8);
        vr[b][0] = *reinterpret_cast<const uint4*>(vp[b] + j1);
        vr[b][1] = *reinterpret_cast<const uint4*>(vp[b] + j1 + 8);
      }
    }

    // bias tile: loaded once, shared by both batches
    f32x4 bv[4];
#pragma unroll
    for (int mt = 0; mt < 4; ++mt)
      bv[mt] = *reinterpret_cast<const f32x4*>(bias_p + j0 + mt * 16);

    // sequential per-b pipeline: only one s[4] live at a time
#pragma unroll
    for (int b = 0; b < 2; ++b) {
      // S^T: D[m=key][n=query] = K·Q^T  (4 key-subtiles x 2 dh-halves)
      f32x4 s[4];
#pragma unroll
      for (int mt = 0; mt < 4; ++mt) {
        const bf16x8 a0 = ld8(&Ks[b][mt * 16 + l15][q4 * 8]);
        const bf16x8 a1 = ld8(&Ks[b][mt * 16 + l15][32 + q4 * 8]);
        f32x4 z = {0.f, 0.f, 0.f, 0.f};
        z = __builtin_amdgcn_mfma_f32_16x16x32_bf16(a0, bq[b][0], z, 0, 0, 0);
        z = __builtin_amdgcn_mfma_f32_16x16x32_bf16(a1, bq[b][1], z, 0, 0, 0);
        s[mt] = z;
      }

      float mx = -1e30f;
#pragma unroll
      for (int mt = 0; mt < 4; ++mt) {
        const f32x4 mv = *reinterpret_cast<const f32x4*>(
            maskA + b * SEQ + j0 + mt * 16 + q4 * 4);
#pragma unroll
        for (int r = 0; r < 4; ++r) {
          s[mt][r] = s[mt][r] + bv[mt][r] + mv[r];
          mx = fmaxf(mx, s[mt][r]);
        }
      }
      mx = fmaxf(mx, __shfl_xor(mx, 16, 64));
      mx = fmaxf(mx, __shfl_xor(mx, 32, 64));
      const float mnew  = fmaxf(m_run[b], mx);
      const float alpha = __builtin_amdgcn_exp2f((m_run[b] - mnew) * L2E);
      const float cc    = -mnew * L2E;
      m_run[b] = mnew;

      float su = 0.0f;
#pragma unroll
      for (int mt = 0; mt < 4; ++mt)
#pragma unroll
        for (int r = 0; r < 4; ++r) {
          s[mt][r] = __builtin_amdgcn_exp2f(__builtin_fmaf(s[mt][r], L2E, cc));
          su += s[mt][r];
        }
      su += __shfl_xor(su, 16, 64);
      su += __shfl_xor(su, 32, 64);
      l_run[b] = l_run[b] * alpha + su;

      // rescale O by alpha of query q4*4+r
#pragma unroll
      for (int r = 0; r < 4; ++r) {
        const float a_r = __shfl(alpha, q4 * 4 + r, 64);
        o[b][0][r] *= a_r; o[b][1][r] *= a_r; o[b][2][r] *= a_r; o[b][3][r] *= a_r;
      }

      // pack P^T (bf16x4 per key-subtile) and transpose to A-layout via shfl
      uint2 pk[4];
#pragma unroll
      for (int mt = 0; mt < 4; ++mt) {
        union { bf16_t hh[4]; uint2 u; } pu;
        pu.hh[0] = (bf16_t)s[mt][0]; pu.hh[1] = (bf16_t)s[mt][1];
        pu.hh[2] = (bf16_t)s[mt][2]; pu.hh[3] = (bf16_t)s[mt][3];
        pk[mt] = pu.u;
      }
      const int src0 = ((q4 & 1) << 5) + l15;   // lane holding keys [base..base+4)
      const int src1 = src0 + 16;               // lane holding keys [base+4..base+8)
      const bool hiSel = (q4 >> 1) != 0;
#pragma unroll
      for (int ks = 0; ks < 2; ++ks) {
        const uint2 a0 = shfl2(pk[2 * ks],     src0);
        const uint2 a1 = shfl2(pk[2 * ks + 1], src0);
        const uint2 b0 = shfl2(pk[2 * ks],     src1);
        const uint2 b1 = shfl2(pk[2 * ks + 1], src1);
        union { unsigned u[4]; bf16x8 v; } pf;
        pf.u[0] = hiSel ? a1.x : a0.x; pf.u[1] = hiSel ? a1.y : a0.y;
        pf.u[2] = hiSel ? b1.x : b0.x; pf.u[3] = hiSel ? b1.y : b0.y;
#pragma unroll
        for (int nt = 0; nt < 4; ++nt) {
          const bf16x8 vv = ld8(&Vs[b][nt * 16 + l15][ks * 32 + q4 * 8]);
          o[b][nt] = __builtin_amdgcn_mfma_f32_16x16x32_bf16(pf.v, vv, o[b][nt], 0, 0, 0);
        }
      }
    }

    __syncthreads();                 // all waves done reading K/V
    if (more) {
#pragma unroll
      for (int b = 0; b < 2; ++b) {
        *reinterpret_cast<uint4*>(&Ks[b][sr][sc])     = kr[b][0];
        *reinterpret_cast<uint4*>(&Ks[b][sr][sc + 8]) = kr[b][1];
        *reinterpret_cast<uint4*>(&Vs[b][sr][sc])     = vr[b][0];
        *reinterpret_cast<uint4*>(&Vs[b][sr][sc + 8]) = vr[b][1];
      }
    }
    __syncthreads();                 // new tiles visible
  }

#pragma unroll
  for (int b = 0; b < 2; ++b)
#pragma unroll
    for (int r = 0; r < 4; ++r) {
      const float linv = 1.0f / __shfl(l_run[b], q4 * 4 + r, 64);
      const int gi = i0 + w * 16 + q4 * 4 + r;
      bf16_t* dst = &aout[((size_t)b * SEQ + gi) * DM + h * HD];
#pragma unroll
      for (int nt = 0; nt < 4; ++nt)
        dst[nt * 16 + l15] = (bf16_t)(o[b][nt][r] * linv);
    }
}

extern "C" void kernel_launch(void* const* d_in, const int* in_sizes, int n_in,
                              void* d_out, int out_size, void* d_ws, size_t ws_size,
                              hipStream_t stream) {
  const float* x         = (const float*)d_in[0];
  const float* attn_bias = (const float*)d_in[1];
  const float* ln_w      = (const float*)d_in[2];
  const float* ln_b      = (const float*)d_in[3];
  const float* wq        = (const float*)d_in[4];
  const float* wkv       = (const float*)d_in[5];
  const float* wo        = (const float*)d_in[6];
  const int*   mask      = (const int*)d_in[7];
  float* out = (float*)d_out;

  char* ws = (char*)d_ws;
  size_t off = 0;
  auto alloc = [&](size_t bytes) {
    char* p = ws + off;
    off += (bytes + 255) & ~(size_t)255;
    return p;
  };
  bf16_t* xbf   = (bf16_t*)alloc((size_t)BB * SEQ * DM * 2);
  bf16_t* xn    = (bf16_t*)alloc((size_t)BB * SEQ * DM * 2);
  bf16_t* wqT   = (bf16_t*)alloc((size_t)DM * DM * 2);
  bf16_t* wkvT  = (bf16_t*)alloc((size_t)2 * HD * DM * 2);
  bf16_t* woT   = (bf16_t*)alloc((size_t)DM * DM * 2);
  bf16_t* qb    = (bf16_t*)alloc((size_t)BB * SEQ * DM * 2);
  bf16_t* kkb   = (bf16_t*)alloc((size_t)BB * SEQ * HD * 2);
  bf16_t* vTb   = (bf16_t*)alloc((size_t)BB * HD * SEQ * 2);
  bf16_t* aoutb = (bf16_t*)alloc((size_t)BB * SEQ * DM * 2);
  float*  maskA = (float*)alloc((size_t)BB * SEQ * 4);

  transpose_cast<<<dim3(DM / 32, DM / 32), 256, 0, stream>>>(wq, wqT, DM, DM);
  transpose_cast<<<dim3(128 / 32, DM / 32), 256, 0, stream>>>(wkv, wkvT, DM, 128);
  transpose_cast<<<dim3(DM / 32, DM / 32), 256, 0, stream>>>(wo, woT, DM, DM);
  row_prep<<<BB * SEQ, 256, 0, stream>>>(x, ln_w, ln_b, mask, xbf, xn, maskA);
  // q = xn @ wq, scaled by DH^-0.5
  gemm128<bf16_t><<<dim3(32, 8), 256, 0, stream>>>(xn, wqT, qb, BB * SEQ, DM, DM, 0.125f);
  // kv = x @ wkv -> K (B,SEQ,64) and V^T (B,64,SEQ)
  gemm_kv<<<dim3(32, 2), 256, 0, stream>>>(xbf, wkvT, kkb, vTb, BB * SEQ, 128, DM);
  // b-paired flash: grid (query tiles, heads)
  flash_attn<<<dim3(SEQ / 64, NHEAD), 256, 0, stream>>>(qb, kkb, vTb, attn_bias,
                                                        maskA, aoutb);
  // out = aout @ wo (fp32 output)
  gemm128<float><<<dim3(32, 8), 256, 0, stream>>>(aoutb, woT, out, BB * SEQ, DM, DM, 1.0f);
}

// Round 6
// 537.751 us; speedup vs baseline: 1.2492x; 1.1849x over previous
//
#include <hip/hip_runtime.h>
#include <hip/hip_bf16.h>

typedef __bf16 bf16_t;
typedef __bf16 bf16x4 __attribute__((ext_vector_type(4)));
typedef __bf16 bf16x8 __attribute__((ext_vector_type(8)));
typedef float f32x4 __attribute__((ext_vector_type(4)));

static constexpr int BB    = 2;
static constexpr int SEQ   = 2048;
static constexpr int DM    = 1024;   // D == INNER
static constexpr int NHEAD = 16;
static constexpr int HD    = 64;
static constexpr float L2E = 1.4426950408889634f;

__device__ __forceinline__ bf16x8 ld8(const bf16_t* p) {
  return *reinterpret_cast<const bf16x8*>(p);
}

// async global->LDS, 16B per lane. LDS dest is wave-uniform base + lane*16.
__device__ __forceinline__ void gl_lds16(const bf16_t* g, bf16_t* l) {
  __builtin_amdgcn_global_load_lds(
      (const __attribute__((address_space(1))) void*)g,
      (__attribute__((address_space(3))) void*)l, 16, 0, 0);
}

__device__ __forceinline__ uint2 shfl2(uint2 v, int src) {
  uint2 r;
  r.x = (unsigned)__shfl((int)v.x, src, 64);
  r.y = (unsigned)__shfl((int)v.y, src, 64);
  return r;
}

template <typename T> __device__ __forceinline__ T cvt_out(float v);
template <> __device__ __forceinline__ float  cvt_out<float >(float v) { return v; }
template <> __device__ __forceinline__ bf16_t cvt_out<bf16_t>(float v) { return (bf16_t)v; }

// ---------------- transpose + cast: in (R,C) fp32 -> out (C,R) bf16 ----------------
__global__ __launch_bounds__(256) void transpose_cast(const float* __restrict__ in,
                                                      bf16_t* __restrict__ out,
                                                      int R, int C) {
  __shared__ float tile[32][33];
  const int c0 = blockIdx.x * 32, r0 = blockIdx.y * 32;
  const int tx = threadIdx.x & 31, ty = threadIdx.x >> 5;
#pragma unroll
  for (int y = ty; y < 32; y += 8)
    tile[y][tx] = in[(size_t)(r0 + y) * C + (c0 + tx)];
  __syncthreads();
#pragma unroll
  for (int y = ty; y < 32; y += 8)
    out[(size_t)(c0 + y) * R + (r0 + tx)] = (bf16_t)tile[tx][y];
}

// -------- LayerNorm row kernel: emits x(bf16), xn(bf16), maskA(float addend) --------
__global__ __launch_bounds__(256) void row_prep(const float* __restrict__ x,
    const float* __restrict__ ln_w, const float* __restrict__ ln_b,
    const int* __restrict__ mask,
    bf16_t* __restrict__ xbf, bf16_t* __restrict__ xn, float* __restrict__ maskA) {
  const int row = blockIdx.x, t = threadIdx.x;
  __shared__ float red[8];
  const float4 xv = *reinterpret_cast<const float4*>(&x[(size_t)row * DM + t * 4]);
  float s  = xv.x + xv.y + xv.z + xv.w;
  float s2 = xv.x * xv.x + xv.y * xv.y + xv.z * xv.z + xv.w * xv.w;
#pragma unroll
  for (int off = 32; off >= 1; off >>= 1) {
    s  += __shfl_xor(s,  off, 64);
    s2 += __shfl_xor(s2, off, 64);
  }
  if ((t & 63) == 0) { red[t >> 6] = s; red[4 + (t >> 6)] = s2; }
  __syncthreads();
  s  = red[0] + red[1] + red[2] + red[3];
  s2 = red[4] + red[5] + red[6] + red[7];
  const float mu   = s * (1.0f / DM);
  const float var  = s2 * (1.0f / DM) - mu * mu;
  const float rstd = rsqrtf(var + 1e-5f);
  const float4 wv = *reinterpret_cast<const float4*>(&ln_w[t * 4]);
  const float4 bv = *reinterpret_cast<const float4*>(&ln_b[t * 4]);
  union { bf16_t h[4]; uint2 u; } p0, p1;
  p0.h[0] = (bf16_t)xv.x; p0.h[1] = (bf16_t)xv.y;
  p0.h[2] = (bf16_t)xv.z; p0.h[3] = (bf16_t)xv.w;
  p1.h[0] = (bf16_t)((xv.x - mu) * rstd * wv.x + bv.x);
  p1.h[1] = (bf16_t)((xv.y - mu) * rstd * wv.y + bv.y);
  p1.h[2] = (bf16_t)((xv.z - mu) * rstd * wv.z + bv.z);
  p1.h[3] = (bf16_t)((xv.w - mu) * rstd * wv.w + bv.w);
  *reinterpret_cast<uint2*>(&xbf[(size_t)row * DM + t * 4]) = p0.u;
  *reinterpret_cast<uint2*>(&xn [(size_t)row * DM + t * 4]) = p1.u;
  if (t == 0) maskA[row] = mask[row] ? 0.0f : -1e30f;
}

// ---- m97-style 128x128 bf16 MFMA GEMM: C(M,Nn) = A(M,K)*Bt(Nn,K)^T, BK=32 ----
template <typename OutT>
__global__ __launch_bounds__(256) void gemm128(const bf16_t* __restrict__ A,
    const bf16_t* __restrict__ Bt, OutT* __restrict__ C,
    int M, int Nn, int K, float scale) {
  __shared__ alignas(16) bf16_t As[128 * 32];
  __shared__ alignas(16) bf16_t Bs[128 * 32];
  const int m0 = blockIdx.x * 128, n0 = blockIdx.y * 128;
  const int t = threadIdx.x, lane = t & 63, w = t >> 6;
  const int wm = (w & 1) * 64, wn = (w >> 1) * 64;
  const int l15 = lane & 15, q4 = lane >> 4;
  f32x4 acc[4][4] = {};
  const int sr = lane >> 2, sc = (lane & 3) * 8;   // 16 rows x 32 cols per issue
  const bf16_t* Ap0 = A  + (size_t)(m0 + w * 32 + sr) * K + sc;
  const bf16_t* Ap1 = Ap0 + (size_t)16 * K;
  const bf16_t* Bp0 = Bt + (size_t)(n0 + w * 32 + sr) * K + sc;
  const bf16_t* Bp1 = Bp0 + (size_t)16 * K;
  bf16_t* AsL0 = &As[(w * 32) * 32];
  bf16_t* AsL1 = &As[(w * 32 + 16) * 32];
  bf16_t* BsL0 = &Bs[(w * 32) * 32];
  bf16_t* BsL1 = &Bs[(w * 32 + 16) * 32];
  for (int k0 = 0; k0 < K; k0 += 32) {
    gl_lds16(Ap0 + k0, AsL0);
    gl_lds16(Ap1 + k0, AsL1);
    gl_lds16(Bp0 + k0, BsL0);
    gl_lds16(Bp1 + k0, BsL1);
    __syncthreads();
    bf16x8 af[4], bfr[4];
#pragma unroll
    for (int mt = 0; mt < 4; ++mt) af[mt]  = ld8(&As[(wm + mt * 16 + l15) * 32 + q4 * 8]);
#pragma unroll
    for (int nt = 0; nt < 4; ++nt) bfr[nt] = ld8(&Bs[(wn + nt * 16 + l15) * 32 + q4 * 8]);
#pragma unroll
    for (int mt = 0; mt < 4; ++mt)
#pragma unroll
      for (int nt = 0; nt < 4; ++nt)
        acc[mt][nt] = __builtin_amdgcn_mfma_f32_16x16x32_bf16(af[mt], bfr[nt], acc[mt][nt], 0, 0, 0);
    __syncthreads();
  }
#pragma unroll
  for (int mt = 0; mt < 4; ++mt)
#pragma unroll
    for (int nt = 0; nt < 4; ++nt)
#pragma unroll
      for (int r = 0; r < 4; ++r) {
        const int gm = m0 + wm + mt * 16 + q4 * 4 + r;
        const int gn = n0 + wn + nt * 16 + l15;
        C[(size_t)gm * Nn + gn] = cvt_out<OutT>(acc[mt][nt][r] * scale);
      }
}

// ---- 128x64 GEMM with kv-split epilogue: C=K (B*SEQ,64), C2=V^T (B,64,SEQ) ----
__global__ __launch_bounds__(256) void gemm_kv(const bf16_t* __restrict__ A,
    const bf16_t* __restrict__ Bt, bf16_t* __restrict__ C, bf16_t* __restrict__ C2,
    int M, int Nn, int K) {
  __shared__ alignas(16) bf16_t As[128 * 32];
  __shared__ alignas(16) bf16_t Bs[64 * 32];
  const int m0 = blockIdx.x * 128, n0 = blockIdx.y * 64;
  const int t = threadIdx.x, lane = t & 63, w = t >> 6;
  const int wm = (w & 1) * 64, wn = (w >> 1) * 32;
  const int l15 = lane & 15, q4 = lane >> 4;
  f32x4 acc[4][2] = {};
  const int sr = lane >> 2, sc = (lane & 3) * 8;
  const bf16_t* Ap0 = A  + (size_t)(m0 + w * 32 + sr) * K + sc;
  const bf16_t* Ap1 = Ap0 + (size_t)16 * K;
  const bf16_t* Bp  = Bt + (size_t)(n0 + w * 16 + sr) * K + sc;
  bf16_t* AsL0 = &As[(w * 32) * 32];
  bf16_t* AsL1 = &As[(w * 32 + 16) * 32];
  bf16_t* BsL  = &Bs[(w * 16) * 32];
  for (int k0 = 0; k0 < K; k0 += 32) {
    gl_lds16(Ap0 + k0, AsL0);
    gl_lds16(Ap1 + k0, AsL1);
    gl_lds16(Bp  + k0, BsL);
    __syncthreads();
    bf16x8 af[4], bfr[2];
#pragma unroll
    for (int mt = 0; mt < 4; ++mt) af[mt]  = ld8(&As[(wm + mt * 16 + l15) * 32 + q4 * 8]);
#pragma unroll
    for (int nt = 0; nt < 2; ++nt) bfr[nt] = ld8(&Bs[(wn + nt * 16 + l15) * 32 + q4 * 8]);
#pragma unroll
    for (int mt = 0; mt < 4; ++mt)
#pragma unroll
      for (int nt = 0; nt < 2; ++nt)
        acc[mt][nt] = __builtin_amdgcn_mfma_f32_16x16x32_bf16(af[mt], bfr[nt], acc[mt][nt], 0, 0, 0);
    __syncthreads();
  }
#pragma unroll
  for (int mt = 0; mt < 4; ++mt)
#pragma unroll
    for (int nt = 0; nt < 2; ++nt)
#pragma unroll
      for (int r = 0; r < 4; ++r) {
        const int gm = m0 + wm + mt * 16 + q4 * 4 + r;
        const int gn = n0 + wn + nt * 16 + l15;
        const bf16_t ov = (bf16_t)acc[mt][nt][r];
        if (gn < HD) C[(size_t)gm * HD + gn] = ov;
        else C2[((size_t)(gm >> 11) * HD + (gn - HD)) * SEQ + (gm & 2047)] = ov;
      }
}

// ------- flash attention v6: b-paired by WAVE-SPLIT (512 threads: waves 0-3
//         handle b=0, waves 4-7 handle b=1, same (h,i0)). Per-thread state is
//         the r3 single-b pipeline (no register doubling -> no spills). Bias
//         addresses identical across the two wave groups -> one L3 read per
//         block. Single-buffered K/V per b, reg-prefetch, shfl P-transpose. ----
__global__ __launch_bounds__(512, 4) void flash_attn(
    const bf16_t* __restrict__ q,     // (B, SEQ, DM), head h at cols h*64..
    const bf16_t* __restrict__ kk,    // (B, SEQ, HD)
    const bf16_t* __restrict__ vT,    // (B, HD, SEQ)
    const float*  __restrict__ bias,  // (NHEAD, SEQ, SEQ)
    const float*  __restrict__ maskA, // (B, SEQ): 0 or -1e30
    bf16_t* __restrict__ aout)        // (B, SEQ, DM)
{
  const int h  = blockIdx.y;          // 16 heads
  const int i0 = blockIdx.x * 64;     // 32 query tiles
  const int t = threadIdx.x, lane = t & 63, w = t >> 6;
  const int bg = w >> 2;              // batch handled by this wave group
  const int wl = w & 3;               // wave within group (query subtile)
  const int l15 = lane & 15, q4 = lane >> 4;

  __shared__ alignas(16) bf16_t Ks[2][64][72];   // [b][key][dh]
  __shared__ alignas(16) bf16_t Vs[2][64][72];   // [b][dh][key]

  // Q fragments (B-operand: B[k=dh][n=query=l15]) for this group's b
  const bf16_t* qrow = &q[((size_t)bg * SEQ + i0 + wl * 16 + l15) * DM + h * HD];
  const bf16x8 bq0 = ld8(qrow + q4 * 8);
  const bf16x8 bq1 = ld8(qrow + 32 + q4 * 8);

  f32x4 o[4] = {};
  float m_run = -1e30f, l_run = 0.0f;

  const float* bias_p = bias + (size_t)h * SEQ * SEQ
                      + (size_t)(i0 + wl * 16 + l15) * SEQ + q4 * 4;
  const float* mask_p = maskA + bg * SEQ + q4 * 4;

  // staging: each 256-thread group stages its own b's K and V tile
  const int tl = t & 255;
  const int sr = tl >> 2, sc = (tl & 3) * 16;
  const bf16_t* kp = &kk[((size_t)bg * SEQ + sr) * HD + sc];
  const bf16_t* vp = &vT[((size_t)bg * HD + sr) * SEQ + sc];

  // prologue: tile 0
  uint4 kr0 = *reinterpret_cast<const uint4*>(kp);
  uint4 kr1 = *reinterpret_cast<const uint4*>(kp + 8);
  uint4 vr0 = *reinterpret_cast<const uint4*>(vp);
  uint4 vr1 = *reinterpret_cast<const uint4*>(vp + 8);
  *reinterpret_cast<uint4*>(&Ks[bg][sr][sc])     = kr0;
  *reinterpret_cast<uint4*>(&Ks[bg][sr][sc + 8]) = kr1;
  *reinterpret_cast<uint4*>(&Vs[bg][sr][sc])     = vr0;
  *reinterpret_cast<uint4*>(&Vs[bg][sr][sc + 8]) = vr1;
  __syncthreads();

  for (int it = 0; it < SEQ / 64; ++it) {
    const int j0 = it * 64;
    const int j1 = j0 + 64;
    const bool more = (j1 < SEQ);
    if (more) {   // reg-prefetch next K/V tile (latency hidden by the body)
      kr0 = *reinterpret_cast<const uint4*>(kp + (size_t)j1 * HD);
      kr1 = *reinterpret_cast<const uint4*>(kp + (size_t)j1 * HD + 8);
      vr0 = *reinterpret_cast<const uint4*>(vp + j1);
      vr1 = *reinterpret_cast<const uint4*>(vp + j1 + 8);
    }

    // bias tile (same addresses in both wave groups -> L2/L3 shared)
    f32x4 bv[4];
#pragma unroll
    for (int mt = 0; mt < 4; ++mt)
      bv[mt] = *reinterpret_cast<const f32x4*>(bias_p + j0 + mt * 16);

    // S^T: D[m=key][n=query] = K·Q^T  (4 key-subtiles x 2 dh-halves)
    f32x4 s[4];
#pragma unroll
    for (int mt = 0; mt < 4; ++mt) {
      const bf16x8 a0 = ld8(&Ks[bg][mt * 16 + l15][q4 * 8]);
      const bf16x8 a1 = ld8(&Ks[bg][mt * 16 + l15][32 + q4 * 8]);
      f32x4 z = {0.f, 0.f, 0.f, 0.f};
      z = __builtin_amdgcn_mfma_f32_16x16x32_bf16(a0, bq0, z, 0, 0, 0);
      z = __builtin_amdgcn_mfma_f32_16x16x32_bf16(a1, bq1, z, 0, 0, 0);
      s[mt] = z;
    }

    float mx = -1e30f;
#pragma unroll
    for (int mt = 0; mt < 4; ++mt) {
      const f32x4 mv = *reinterpret_cast<const f32x4*>(mask_p + j0 + mt * 16);
#pragma unroll
      for (int r = 0; r < 4; ++r) {
        s[mt][r] = s[mt][r] + bv[mt][r] + mv[r];
        mx = fmaxf(mx, s[mt][r]);
      }
    }
    mx = fmaxf(mx, __shfl_xor(mx, 16, 64));
    mx = fmaxf(mx, __shfl_xor(mx, 32, 64));
    const float mnew  = fmaxf(m_run, mx);
    const float alpha = __builtin_amdgcn_exp2f((m_run - mnew) * L2E);
    const float cc    = -mnew * L2E;
    m_run = mnew;

    float su = 0.0f;
#pragma unroll
    for (int mt = 0; mt < 4; ++mt)
#pragma unroll
      for (int r = 0; r < 4; ++r) {
        s[mt][r] = __builtin_amdgcn_exp2f(__builtin_fmaf(s[mt][r], L2E, cc));
        su += s[mt][r];
      }
    su += __shfl_xor(su, 16, 64);
    su += __shfl_xor(su, 32, 64);
    l_run = l_run * alpha + su;

    // rescale O by alpha of query q4*4+r
#pragma unroll
    for (int r = 0; r < 4; ++r) {
      const float a_r = __shfl(alpha, q4 * 4 + r, 64);
      o[0][r] *= a_r; o[1][r] *= a_r; o[2][r] *= a_r; o[3][r] *= a_r;
    }

    // pack P^T (bf16x4 per key-subtile) and transpose to A-layout via shfl
    uint2 pk[4];
#pragma unroll
    for (int mt = 0; mt < 4; ++mt) {
      union { bf16_t hh[4]; uint2 u; } pu;
      pu.hh[0] = (bf16_t)s[mt][0]; pu.hh[1] = (bf16_t)s[mt][1];
      pu.hh[2] = (bf16_t)s[mt][2]; pu.hh[3] = (bf16_t)s[mt][3];
      pk[mt] = pu.u;
    }
    const int src0 = ((q4 & 1) << 5) + l15;   // lane holding keys [base..base+4)
    const int src1 = src0 + 16;               // lane holding keys [base+4..base+8)
    const bool hiSel = (q4 >> 1) != 0;
#pragma unroll
    for (int ks = 0; ks < 2; ++ks) {
      const uint2 a0 = shfl2(pk[2 * ks],     src0);
      const uint2 a1 = shfl2(pk[2 * ks + 1], src0);
      const uint2 b0 = shfl2(pk[2 * ks],     src1);
      const uint2 b1 = shfl2(pk[2 * ks + 1], src1);
      union { unsigned u[4]; bf16x8 v; } pf;
      pf.u[0] = hiSel ? a1.x : a0.x; pf.u[1] = hiSel ? a1.y : a0.y;
      pf.u[2] = hiSel ? b1.x : b0.x; pf.u[3] = hiSel ? b1.y : b0.y;
#pragma unroll
      for (int nt = 0; nt < 4; ++nt) {
        const bf16x8 vv = ld8(&Vs[bg][nt * 16 + l15][ks * 32 + q4 * 8]);
        o[nt] = __builtin_amdgcn_mfma_f32_16x16x32_bf16(pf.v, vv, o[nt], 0, 0, 0);
      }
    }

    __syncthreads();                 // all waves done reading K/V
    if (more) {
      *reinterpret_cast<uint4*>(&Ks[bg][sr][sc])     = kr0;
      *reinterpret_cast<uint4*>(&Ks[bg][sr][sc + 8]) = kr1;
      *reinterpret_cast<uint4*>(&Vs[bg][sr][sc])     = vr0;
      *reinterpret_cast<uint4*>(&Vs[bg][sr][sc + 8]) = vr1;
    }
    __syncthreads();                 // new tiles visible
  }

#pragma unroll
  for (int r = 0; r < 4; ++r) {
    const float linv = 1.0f / __shfl(l_run, q4 * 4 + r, 64);
    const int gi = i0 + wl * 16 + q4 * 4 + r;
    bf16_t* dst = &aout[((size_t)bg * SEQ + gi) * DM + h * HD];
#pragma unroll
    for (int nt = 0; nt < 4; ++nt)
      dst[nt * 16 + l15] = (bf16_t)(o[nt][r] * linv);
  }
}

extern "C" void kernel_launch(void* const* d_in, const int* in_sizes, int n_in,
                              void* d_out, int out_size, void* d_ws, size_t ws_size,
                              hipStream_t stream) {
  const float* x         = (const float*)d_in[0];
  const float* attn_bias = (const float*)d_in[1];
  const float* ln_w      = (const float*)d_in[2];
  const float* ln_b      = (const float*)d_in[3];
  const float* wq        = (const float*)d_in[4];
  const float* wkv       = (const float*)d_in[5];
  const float* wo        = (const float*)d_in[6];
  const int*   mask      = (const int*)d_in[7];
  float* out = (float*)d_out;

  char* ws = (char*)d_ws;
  size_t off = 0;
  auto alloc = [&](size_t bytes) {
    char* p = ws + off;
    off += (bytes + 255) & ~(size_t)255;
    return p;
  };
  bf16_t* xbf   = (bf16_t*)alloc((size_t)BB * SEQ * DM * 2);
  bf16_t* xn    = (bf16_t*)alloc((size_t)BB * SEQ * DM * 2);
  bf16_t* wqT   = (bf16_t*)alloc((size_t)DM * DM * 2);
  bf16_t* wkvT  = (bf16_t*)alloc((size_t)2 * HD * DM * 2);
  bf16_t* woT   = (bf16_t*)alloc((size_t)DM * DM * 2);
  bf16_t* qb    = (bf16_t*)alloc((size_t)BB * SEQ * DM * 2);
  bf16_t* kkb   = (bf16_t*)alloc((size_t)BB * SEQ * HD * 2);
  bf16_t* vTb   = (bf16_t*)alloc((size_t)BB * HD * SEQ * 2);
  bf16_t* aoutb = (bf16_t*)alloc((size_t)BB * SEQ * DM * 2);
  float*  maskA = (float*)alloc((size_t)BB * SEQ * 4);

  transpose_cast<<<dim3(DM / 32, DM / 32), 256, 0, stream>>>(wq, wqT, DM, DM);
  transpose_cast<<<dim3(128 / 32, DM / 32), 256, 0, stream>>>(wkv, wkvT, DM, 128);
  transpose_cast<<<dim3(DM / 32, DM / 32), 256, 0, stream>>>(wo, woT, DM, DM);
  row_prep<<<BB * SEQ, 256, 0, stream>>>(x, ln_w, ln_b, mask, xbf, xn, maskA);
  // q = xn @ wq, scaled by DH^-0.5
  gemm128<bf16_t><<<dim3(32, 8), 256, 0, stream>>>(xn, wqT, qb, BB * SEQ, DM, DM, 0.125f);
  // kv = x @ wkv -> K (B,SEQ,64) and V^T (B,64,SEQ)
  gemm_kv<<<dim3(32, 2), 256, 0, stream>>>(xbf, wkvT, kkb, vTb, BB * SEQ, 128, DM);
  // b-paired flash via wave-split: grid (query tiles, heads), 512 threads
  flash_attn<<<dim3(SEQ / 64, NHEAD), 512, 0, stream>>>(qb, kkb, vTb, attn_bias,
                                                        maskA, aoutb);
  // out = aout @ wo (fp32 output)
  gemm128<float><<<dim3(32, 8), 256, 0, stream>>>(aoutb, woT, out, BB * SEQ, DM, DM, 1.0f);
}